// Round 20
// baseline (135.567 us; speedup 1.0000x reference)
//
#include <hip/hip_runtime.h>
#include <hip/hip_bf16.h>
#include <math.h>

#define PI4F 0.78539816339744830962f

typedef __attribute__((ext_vector_type(2))) __bf16 bf16x2_t;
typedef __attribute__((ext_vector_type(8))) short s8v;      // bf16x8 MFMA operand
typedef __attribute__((ext_vector_type(4))) float f32x4;    // MFMA accumulator
typedef __attribute__((ext_vector_type(4))) unsigned int uint4v;

__device__ __forceinline__ float dot2bf(unsigned int a, unsigned int b, float c) {
#if defined(__has_builtin) && __has_builtin(__builtin_amdgcn_fdot2_f32_bf16)
    return __builtin_amdgcn_fdot2_f32_bf16(__builtin_bit_cast(bf16x2_t, a),
                                           __builtin_bit_cast(bf16x2_t, b), c, false);
#else
    float a0 = __uint_as_float(a << 16), a1 = __uint_as_float(a & 0xffff0000u);
    float b0 = __uint_as_float(b << 16), b1 = __uint_as_float(b & 0xffff0000u);
    return fmaf(a1, b1, fmaf(a0, b0, c));
#endif
}

__device__ __forceinline__ unsigned short bf16bits(float v) {
    return __builtin_bit_cast(unsigned short, __float2bfloat16(v));
}
__device__ __forceinline__ unsigned int packbf(float lo, float hi) {
    return (unsigned int)bf16bits(lo) | ((unsigned int)bf16bits(hi) << 16);
}
__device__ __forceinline__ float ubf_lo(unsigned int u) { return __uint_as_float(u << 16); }
__device__ __forceinline__ float ubf_hi(unsigned int u) { return __uint_as_float(u & 0xffff0000u); }

// ---------------- Kernel 1: global average pool (float4) ----------------
__global__ void k_pool(const float* __restrict__ x, float* __restrict__ pooled) {
    int bc = blockIdx.x;
    const float4* p4 = (const float4*)(x + (size_t)bc * 16384);
    float s = 0.f;
    for (int j = threadIdx.x; j < 4096; j += 256) {
        float4 v = p4[j];
        s += (v.x + v.y) + (v.z + v.w);
    }
    for (int off = 32; off > 0; off >>= 1) s += __shfl_xor(s, off, 64);
    __shared__ float red[4];
    int wave = threadIdx.x >> 6;
    if ((threadIdx.x & 63) == 0) red[wave] = s;
    __syncthreads();
    if (threadIdx.x == 0) {
        float t = red[0] + red[1] + red[2] + red[3];
        pooled[bc] = t * (1.0f / 16384.0f);
    }
}

// ---------------- Kernel 2: small MLPs -> angles, mod ----------------
__global__ void k_mlp(const float* __restrict__ pooled,
                      const float* __restrict__ aw1, const float* __restrict__ ab1,
                      const float* __restrict__ aw2, const float* __restrict__ ab2,
                      const float* __restrict__ mw1, const float* __restrict__ mb1,
                      const float* __restrict__ mw2, const float* __restrict__ mb2,
                      float* __restrict__ angles, float* __restrict__ mod) {
    int i = blockIdx.x >> 3, b = blockIdx.x & 7;
    int t = threadIdx.x;
    __shared__ float sp[64], sha[16], shm[16];
    sp[t] = pooled[b * 64 + t];
    __syncthreads();
    if (t < 16) {
        float sa = ab1[i * 16 + t], sm = mb1[i * 16 + t];
        const float* wa = aw1 + ((size_t)i * 16 + t) * 64;
        const float* wm = mw1 + ((size_t)i * 16 + t) * 64;
        for (int c = 0; c < 64; ++c) { sa = fmaf(wa[c], sp[c], sa); sm = fmaf(wm[c], sp[c], sm); }
        sha[t] = fmaxf(sa, 0.f);
        shm[t] = fmaxf(sm, 0.f);
    }
    __syncthreads();
    if (t < 8) {
        float s = ab2[i * 8 + t];
        const float* w = aw2 + ((size_t)i * 8 + t) * 16;
        for (int j = 0; j < 16; ++j) s = fmaf(w[j], sha[j], s);
        angles[i * 64 + b * 8 + t] = tanhf(s) * PI4F;
    }
    {
        float s = mb2[i * 64 + t];
        const float* w = mw2 + ((size_t)i * 64 + t) * 16;
        for (int j = 0; j < 16; ++j) s = fmaf(w[j], shm[j], s);
        mod[i * 512 + b * 64 + t] = 1.f / (1.f + expf(-s));
    }
}

// ---------------- Kernel 3: rotate base kernels -> MFMA-friendly bf16 pairs ----------------
__global__ void k_rot(const float* __restrict__ bk, const float* __restrict__ angles,
                      unsigned int* __restrict__ rotp) {
    int blk = blockIdx.x;
    int g = blk & 7, b = (blk >> 3) & 7, i = blk >> 6;
    float ang = angles[i * 64 + b * 8 + g];
    float st, ct;
    sincosf(ang, &st, &ct);
    int t = threadIdx.x;
    int co = t >> 3, ci = t & 7;
    const float* K = bk + ((((size_t)i * 8 + g) * 8 + co) * 8 + ci) * 9;
    __shared__ float tmp[576];
#pragma unroll
    for (int p = 0; p < 9; ++p) {
        int ky = p / 3, kx = p % 3;
        float xx = (float)kx - 1.f, yy = (float)ky - 1.f;
        float xr = xx * ct + yy * st + 1.f;
        float yr = -xx * st + yy * ct + 1.f;
        float x0 = fminf(fmaxf(floorf(xr), 0.f), 1.f);
        float y0 = fminf(fmaxf(floorf(yr), 0.f), 1.f);
        float x1 = x0 + 1.f, y1 = y0 + 1.f;
        float w00 = (x1 - xr) * (y1 - yr);
        float w01 = (x1 - xr) * (yr - y0);
        float w10 = (xr - x0) * (y1 - yr);
        float w11 = (xr - x0) * (yr - y0);
        int x0i = (int)x0, y0i = (int)y0;
        float v = w00 * K[y0i * 3 + x0i] + w01 * K[(y0i + 1) * 3 + x0i]
                + w10 * K[y0i * 3 + x0i + 1] + w11 * K[(y0i + 1) * 3 + x0i + 1];
        tmp[t * 9 + p] = v;
    }
    __syncthreads();
    unsigned int* R = rotp + (size_t)blk * 384;
    for (int ot = t; ot < 384; ot += 64) {
        int co2 = ot / 48;
        int rem = ot - co2 * 48;
        int tap = rem >> 2;
        int q = rem & 3;
        unsigned int val = 0u;
        if (tap < 9) {
            float v0 = tmp[(co2 * 8 + 2 * q) * 9 + tap];
            float v1 = tmp[(co2 * 8 + 2 * q + 1) * 9 + tap];
            val = packbf(v0, v1);
        }
        R[ot] = val;
    }
}

// ---------------- Kernel 3.5: prep (w1f, e1f, ew2p) ----------------
__global__ void k_prep(const float* __restrict__ w1,
                       const float* __restrict__ bnw, const float* __restrict__ bnb,
                       const float* __restrict__ bnm, const float* __restrict__ bnv,
                       const float* __restrict__ ew1,
                       const float* __restrict__ ebnw, const float* __restrict__ ebnb,
                       const float* __restrict__ ebnm, const float* __restrict__ ebnv,
                       const float* __restrict__ ew2,
                       unsigned int* __restrict__ w1f, float* __restrict__ dsh,
                       unsigned int* __restrict__ e1f, float* __restrict__ esh,
                       unsigned int* __restrict__ ew2p) {
    int tid = threadIdx.x;
    __shared__ float sc[64], sce[32];
    if (tid < 64) {
        float s = bnw[tid] * rsqrtf(bnv[tid] + 1e-5f);
        sc[tid] = s;
        dsh[tid] = bnb[tid] - bnm[tid] * s;
    }
    if (tid < 32) {
        float s = ebnw[tid] * rsqrtf(ebnv[tid] + 1e-5f);
        sce[tid] = s;
        esh[tid] = ebnb[tid] - ebnm[tid] * s;
    }
    __syncthreads();
    for (int q = tid; q < 8192; q += 256) {
        int jp = q & 3;
        int l  = (q >> 2) & 63;
        int ks = (q >> 8) & 7;
        int nt = q >> 11;
        int o = nt * 16 + (l & 15);
        int k = ks * 32 + (l >> 4) * 8 + jp * 2;
        w1f[q] = packbf(w1[o * 256 + k] * sc[o], w1[o * 256 + k + 1] * sc[o]);
    }
    for (int q = tid; q < 4096; q += 256) {
        int jp = q & 3;
        int l  = (q >> 2) & 63;
        int kss = (q >> 8) & 1;
        int nt8 = q >> 9;
        int o = (nt8 & 1) * 16 + (l & 15);
        int kloc = kss * 32 + (l >> 4) * 8 + jp * 2;
        e1f[q] = packbf(ew1[o * 64 + kloc] * sce[o], ew1[o * 64 + kloc + 1] * sce[o]);
    }
    for (int q = tid; q < 1024; q += 256) {
        int cc = q >> 4, c2 = q & 15;
        ew2p[q] = packbf(ew2[cc * 32 + 2 * c2], ew2[cc * 32 + 2 * c2 + 1]);
    }
}

// ---------------- Kernel 4 (unchanged): MFMA conv, pair-packed u32 out ----------------
__global__ void __launch_bounds__(256) k_conv(const float* __restrict__ x,
                       const unsigned int* __restrict__ rotp, const float* __restrict__ mod,
                       unsigned int* __restrict__ bfu) {
    __shared__ unsigned int s_in[1156 * 6];     // 27744 B
    unsigned short* s16 = (unsigned short*)s_in;

    int bg = blockIdx.y;
    int b = bg >> 3, g = bg & 7;
    int tile_h0 = (blockIdx.x >> 2) * 32;
    int tile_w0 = (blockIdx.x & 3) * 32;
    int tid = threadIdx.x;

    const float* xg = x + ((size_t)b * 64 + (size_t)g * 8) * 16384;
    for (int idx = tid; idx < 8 * 1156; idx += 256) {
        int ci = idx / 1156;
        int pix = idx - ci * 1156;
        int r = pix / 34;
        int c = pix - r * 34;
        int gh = tile_h0 + r - 1;
        int gw = tile_w0 + c - 1;
        float v = 0.f;
        if (gh >= 0 && gh < 128 && gw >= 0 && gw < 128)
            v = xg[(size_t)ci * 16384 + gh * 128 + gw];
        s16[pix * 12 + ci] = bf16bits(v);
    }
    __syncthreads();

    int l = tid & 63, wv = tid >> 6;
    int n = l & 15;
    int kg = l >> 4;

    s8v Bf[2][3];
    float mv[2];
#pragma unroll
    for (int bp = 0; bp < 2; ++bp) {
        int i = bp * 2 + (n >> 3);
        int co = n & 7;
        mv[bp] = mod[i * 512 + b * 64 + g * 8 + co];
#pragma unroll
        for (int ks = 0; ks < 3; ++ks) {
            int tap = ks * 4 + kg;
            const uint4v* src = (const uint4v*)(rotp
                + ((size_t)((i * 8 + b) * 8 + g)) * 384 + co * 48 + tap * 4);
            Bf[bp][ks] = __builtin_bit_cast(s8v, *src);
        }
    }

    int hoff6[3];
#pragma unroll
    for (int ks = 0; ks < 3; ++ks) {
        int tap = ks * 4 + kg;
        int t9 = tap > 8 ? 8 : tap;
        int ky = t9 >= 6 ? 2 : (t9 >= 3 ? 1 : 0);
        int kx = t9 - ky * 3;
        hoff6[ks] = (ky * 34 + kx) * 6;
    }

#pragma unroll 2
    for (int t = 0; t < 16; ++t) {
        int px0 = wv * 256 + t * 16;
        int trow = px0 >> 5;
        int tcolb = px0 & 31;
        int basedw = (trow * 34 + tcolb + n) * 6;

        s8v Af[3];
#pragma unroll
        for (int ks = 0; ks < 3; ++ks) {
            const uint2* pa = (const uint2*)(s_in + basedw + hoff6[ks]);
            uint2 v01 = pa[0];
            uint2 v23 = pa[1];
            uint4v au; au.x = v01.x; au.y = v01.y; au.z = v23.x; au.w = v23.y;
            Af[ks] = __builtin_bit_cast(s8v, au);
        }

#pragma unroll
        for (int bp = 0; bp < 2; ++bp) {
            f32x4 acc = (f32x4){0.f, 0.f, 0.f, 0.f};
#pragma unroll
            for (int ks = 0; ks < 3; ++ks)
                acc = __builtin_amdgcn_mfma_f32_16x16x32_bf16(Af[ks], Bf[bp][ks], acc, 0, 0, 0);

            int i = bp * 2 + (n >> 3);
            int co = n & 7;
            float a0 = acc[0] * mv[bp], a1 = acc[1] * mv[bp];
            float a2 = acc[2] * mv[bp], a3 = acc[3] * mv[bp];
            float p0 = __shfl_xor(a0, 1, 64);
            float p1 = __shfl_xor(a1, 1, 64);
            float p2 = __shfl_xor(a2, 1, 64);
            float p3 = __shfl_xor(a3, 1, 64);
            if (!(n & 1)) {
                int pxo = px0 + kg * 4;
                int orow = pxo >> 5, ocol = pxo & 31;
                uint4v st;
                st.x = packbf(a0, p0);
                st.y = packbf(a1, p1);
                st.z = packbf(a2, p2);
                st.w = packbf(a3, p3);
                unsigned int* opu = bfu
                    + (((size_t)(i * 8 + b) * 32) + g * 4 + (co >> 1)) * 16384
                    + (tile_h0 + orow) * 128 + tile_w0 + ocol;
                *(uint4v*)opu = st;
            }
        }
    }
}

// ---------------- Kernel 5 (v16): merged-pass MFMA + launch_bounds(256,2) ----------------
// 2 waves/EU declared -> 256-VGPR budget; acc(64)+acc2(128) stay in registers.
__global__ void __launch_bounds__(256, 2) k_mega(
    const float* __restrict__ x, const unsigned int* __restrict__ bfu,
    const float* __restrict__ roi,
    const unsigned int* __restrict__ w1f, const float* __restrict__ dsh,
    const float* __restrict__ w2, const float* __restrict__ b2,
    const unsigned int* __restrict__ e1f, const float* __restrict__ esh,
    const unsigned int* __restrict__ ew2p, const float* __restrict__ eb2,
    float* __restrict__ out) {

    __shared__ unsigned short y_lds[256 * 72];   // 36864 B

    int tid = threadIdx.x;
    int p = blockIdx.x * 256 + tid;
    int b = p >> 14;
    int hw = p & 16383;
    int h = hw >> 7, w = hw & 127;
    int hw_base = (blockIdx.x & 63) * 256;

    int l = tid & 63, wv = tid >> 6;
    int arow = l & 15, kg = l >> 4;

    // ---- roi bilinear (early; hides under MFMA) ----
    float ysv = (float)h * (63.f / 127.f);
    float y0f = fminf(floorf(ysv), 62.f);
    float wy = ysv - y0f;
    float xsv = (float)w * (63.f / 127.f);
    float x0f = fminf(floorf(xsv), 62.f);
    float wx = xsv - x0f;
    int y0i = (int)y0f, x0i = (int)x0f;
    const float* rb = roi + (size_t)b * 4096;
    float r00 = rb[y0i * 64 + x0i], r01 = rb[y0i * 64 + x0i + 1];
    float r10 = rb[(y0i + 1) * 64 + x0i], r11 = rb[(y0i + 1) * 64 + x0i + 1];
    float rv = r00 * (1.f - wy) * (1.f - wx) + r01 * (1.f - wy) * wx
             + r10 * wy * (1.f - wx) + r11 * wy * wx;

    // ---- merged MFMA loop: y (4 nt) + m (2 nt8) per ks, shared A-frags ----
    f32x4 acc[4][4];
#pragma unroll
    for (int mt = 0; mt < 4; ++mt)
#pragma unroll
        for (int nt = 0; nt < 4; ++nt)
            acc[mt][nt] = (f32x4){0.f, 0.f, 0.f, 0.f};
    f32x4 acc2[8][4];   // [nt8][mt]
#pragma unroll
    for (int nt8 = 0; nt8 < 8; ++nt8)
#pragma unroll
        for (int mt = 0; mt < 4; ++mt)
            acc2[nt8][mt] = (f32x4){0.f, 0.f, 0.f, 0.f};

#pragma unroll 2
    for (int ks = 0; ks < 8; ++ks) {
        int k0 = ks * 32 + kg * 8;
        size_t pbase = ((size_t)((k0 >> 6) * 8 + b) * 32 + ((k0 & 63) >> 1)) * 16384;
        s8v af[4];
#pragma unroll
        for (int mt = 0; mt < 4; ++mt) {
            const unsigned int* q = bfu + pbase + hw_base + wv * 64 + mt * 16 + arow;
            uint4v au;
            au.x = q[0];
            au.y = q[16384];
            au.z = q[32768];
            au.w = q[49152];
            af[mt] = __builtin_bit_cast(s8v, au);
        }
        // y MFMAs
        s8v bfr[4];
#pragma unroll
        for (int nt = 0; nt < 4; ++nt) {
            uint4v bu = *(const uint4v*)(w1f + (((nt * 8 + ks) * 64 + l) << 2));
            bfr[nt] = __builtin_bit_cast(s8v, bu);
        }
#pragma unroll
        for (int mt = 0; mt < 4; ++mt)
#pragma unroll
            for (int nt = 0; nt < 4; ++nt)
                acc[mt][nt] = __builtin_amdgcn_mfma_f32_16x16x32_bf16(
                    af[mt], bfr[nt], acc[mt][nt], 0, 0, 0);
        // m MFMAs (block-diagonal: 2 nt8 per ks), same af
        int kss = ks & 1;
#pragma unroll
        for (int t2 = 0; t2 < 2; ++t2) {
            int nt8 = (ks >> 1) * 2 + t2;
            uint4v bu = *(const uint4v*)(e1f + ((nt8 * 2 + kss) * 256 + l * 4));
            s8v bq = __builtin_bit_cast(s8v, bu);
#pragma unroll
            for (int mt = 0; mt < 4; ++mt)
                acc2[nt8][mt] = __builtin_amdgcn_mfma_f32_16x16x32_bf16(
                    af[mt], bq, acc2[nt8][mt], 0, 0, 0);
        }
    }

    // ---- scatter y to LDS ----
#pragma unroll
    for (int mt = 0; mt < 4; ++mt)
#pragma unroll
        for (int nt = 0; nt < 4; ++nt)
#pragma unroll
            for (int r = 0; r < 4; ++r) {
                int px = wv * 64 + mt * 16 + kg * 4 + r;
                y_lds[px * 72 + nt * 16 + arow] = bf16bits(acc[mt][nt][r]);
            }
    __syncthreads();

    // ---- gather y, bias + relu ----
    float y[64];
    {
        const uint4v* yr = (const uint4v*)(y_lds + (size_t)tid * 72);
#pragma unroll
        for (int q8 = 0; q8 < 8; ++q8) {
            uint4v v = yr[q8];
            y[q8 * 8 + 0] = ubf_lo(v.x); y[q8 * 8 + 1] = ubf_hi(v.x);
            y[q8 * 8 + 2] = ubf_lo(v.y); y[q8 * 8 + 3] = ubf_hi(v.y);
            y[q8 * 8 + 4] = ubf_lo(v.z); y[q8 * 8 + 5] = ubf_hi(v.z);
            y[q8 * 8 + 6] = ubf_lo(v.w); y[q8 * 8 + 7] = ubf_hi(v.w);
        }
    }
#pragma unroll
    for (int o = 0; o < 64; ++o) y[o] = fmaxf(y[o] + dsh[o], 0.f);

    // ---- phase 2: logits + softmax ----
    float lg[4];
#pragma unroll
    for (int k = 0; k < 4; ++k) {
        float s = b2[k];
        const float* wr = w2 + k * 64;                   // uniform
#pragma unroll
        for (int o = 0; o < 64; ++o) s = fmaf(wr[o], y[o], s);
        lg[k] = s;
    }
    float mx = fmaxf(fmaxf(lg[0], lg[1]), fmaxf(lg[2], lg[3]));
    float e0 = expf(lg[0] - mx), e1s = expf(lg[1] - mx), e2s = expf(lg[2] - mx), e3s = expf(lg[3] - mx);
    float inv = 1.f / (e0 + e1s + e2s + e3s);
    float ar = inv * rv;
    float ar0 = e0 * ar, ar1 = e1s * ar, ar2 = e2s * ar, ar3 = e3s * ar;

    float t[32];
#pragma unroll
    for (int o = 0; o < 32; ++o) t[o] = esh[o];

    // ---- round B: m0,m1 ----
    __syncthreads();
#pragma unroll
    for (int nt8 = 0; nt8 < 4; ++nt8)
#pragma unroll
        for (int mt = 0; mt < 4; ++mt)
#pragma unroll
            for (int r = 0; r < 4; ++r) {
                int px = wv * 64 + mt * 16 + kg * 4 + r;
                y_lds[px * 72 + nt8 * 16 + arow] = bf16bits(acc2[nt8][mt][r]);
            }
    __syncthreads();
    {
        const uint4v* yr = (const uint4v*)(y_lds + (size_t)tid * 72);
#pragma unroll
        for (int q8 = 0; q8 < 8; ++q8) {
            uint4v v = yr[q8];
            float arq = (q8 < 4) ? ar0 : ar1;
            int base = (q8 & 3) * 8;
            t[base + 0] = fmaf(arq, ubf_lo(v.x), t[base + 0]);
            t[base + 1] = fmaf(arq, ubf_hi(v.x), t[base + 1]);
            t[base + 2] = fmaf(arq, ubf_lo(v.y), t[base + 2]);
            t[base + 3] = fmaf(arq, ubf_hi(v.y), t[base + 3]);
            t[base + 4] = fmaf(arq, ubf_lo(v.z), t[base + 4]);
            t[base + 5] = fmaf(arq, ubf_hi(v.z), t[base + 5]);
            t[base + 6] = fmaf(arq, ubf_lo(v.w), t[base + 6]);
            t[base + 7] = fmaf(arq, ubf_hi(v.w), t[base + 7]);
        }
    }

    // ---- round C: m2,m3 ----
    __syncthreads();
#pragma unroll
    for (int nt8 = 4; nt8 < 8; ++nt8)
#pragma unroll
        for (int mt = 0; mt < 4; ++mt)
#pragma unroll
            for (int r = 0; r < 4; ++r) {
                int px = wv * 64 + mt * 16 + kg * 4 + r;
                y_lds[px * 72 + (nt8 - 4) * 16 + arow] = bf16bits(acc2[nt8][mt][r]);
            }
    __syncthreads();
    {
        const uint4v* yr = (const uint4v*)(y_lds + (size_t)tid * 72);
#pragma unroll
        for (int q8 = 0; q8 < 8; ++q8) {
            uint4v v = yr[q8];
            float arq = (q8 < 4) ? ar2 : ar3;
            int base = (q8 & 3) * 8;
            t[base + 0] = fmaf(arq, ubf_lo(v.x), t[base + 0]);
            t[base + 1] = fmaf(arq, ubf_hi(v.x), t[base + 1]);
            t[base + 2] = fmaf(arq, ubf_lo(v.y), t[base + 2]);
            t[base + 3] = fmaf(arq, ubf_hi(v.y), t[base + 3]);
            t[base + 4] = fmaf(arq, ubf_lo(v.z), t[base + 4]);
            t[base + 5] = fmaf(arq, ubf_hi(v.z), t[base + 5]);
            t[base + 6] = fmaf(arq, ubf_lo(v.w), t[base + 6]);
            t[base + 7] = fmaf(arq, ubf_hi(v.w), t[base + 7]);
        }
    }

    // ---- eh = relu(t), pack ----
    unsigned int ehp[16];
#pragma unroll
    for (int q = 0; q < 16; ++q)
        ehp[q] = packbf(fmaxf(t[2 * q], 0.f), fmaxf(t[2 * q + 1], 0.f));

    // ---- phase 6: e2 = sigmoid(ew2 @ eh + b), out = x*(1+e2) ----
    const float* xp = x + ((size_t)b * 64) * 16384 + hw;
    float* op = out + ((size_t)b * 64) * 16384 + hw;
#pragma unroll 8
    for (int cc = 0; cc < 64; ++cc) {
        float s = eb2[cc];
        const unsigned int* wr = ew2p + cc * 16;         // uniform -> SGPR
#pragma unroll
        for (int q = 0; q < 16; ++q) s = dot2bf(ehp[q], wr[q], s);
        float sg = 1.f / (1.f + expf(-s));
        float xv = xp[(size_t)cc * 16384];
        op[(size_t)cc * 16384] = xv + xv * sg;
    }
}

extern "C" void kernel_launch(void* const* d_in, const int* in_sizes, int n_in,
                              void* d_out, int out_size, void* d_ws, size_t ws_size,
                              hipStream_t stream) {
    const float* x    = (const float*)d_in[0];
    const float* roi  = (const float*)d_in[1];
    const float* bk   = (const float*)d_in[2];
    const float* aw1  = (const float*)d_in[3];
    const float* ab1  = (const float*)d_in[4];
    const float* aw2  = (const float*)d_in[5];
    const float* ab2  = (const float*)d_in[6];
    const float* mw1  = (const float*)d_in[7];
    const float* mb1  = (const float*)d_in[8];
    const float* mw2  = (const float*)d_in[9];
    const float* mb2  = (const float*)d_in[10];
    const float* w1   = (const float*)d_in[11];
    const float* bnw  = (const float*)d_in[12];
    const float* bnb  = (const float*)d_in[13];
    const float* bnm  = (const float*)d_in[14];
    const float* bnv  = (const float*)d_in[15];
    const float* w2   = (const float*)d_in[16];
    const float* b2   = (const float*)d_in[17];
    const float* ew1  = (const float*)d_in[18];
    const float* ebnw = (const float*)d_in[19];
    const float* ebnb = (const float*)d_in[20];
    const float* ebnm = (const float*)d_in[21];
    const float* ebnv = (const float*)d_in[22];
    const float* ew2  = (const float*)d_in[23];
    const float* eb2  = (const float*)d_in[24];

    float* ws     = (float*)d_ws;
    float* pooled = ws;                    // 512
    float* angles = ws + 512;              // 256
    float* mod    = ws + 768;              // 2048
    unsigned int* rotp = (unsigned int*)(ws + 2816);   // 98304 u32
    unsigned int* w1f  = (unsigned int*)(ws + 150272); // 8192 u32
    float* dsh    = ws + 158464;           // 64
    float* esh    = ws + 158528;           // 32
    unsigned int* ew2p = (unsigned int*)(ws + 158560); // 1024
    unsigned int* e1f  = (unsigned int*)(ws + 159584); // 4096
    unsigned int* bfu  = (unsigned int*)(ws + 166720); // 16M u32 = 64 MB

    k_prep<<<1, 256, 0, stream>>>(w1, bnw, bnb, bnm, bnv,
                                  ew1, ebnw, ebnb, ebnm, ebnv, ew2,
                                  w1f, dsh, e1f, esh, ew2p);
    k_pool<<<512, 256, 0, stream>>>(x, pooled);
    k_mlp<<<32, 64, 0, stream>>>(pooled, aw1, ab1, aw2, ab2, mw1, mb1, mw2, mb2, angles, mod);
    k_rot<<<256, 64, 0, stream>>>(bk, angles, rotp);
    k_conv<<<dim3(16, 64), 256, 0, stream>>>(x, rotp, mod, bfu);
    k_mega<<<512, 256, 0, stream>>>(x, bfu, roi, w1f, dsh, w2, b2,
                                    e1f, esh, ew2p, eb2,
                                    (float*)d_out);
}

// Round 21
// 93.390 us; speedup vs baseline: 1.4516x; 1.4516x over previous
//
#include <hip/hip_runtime.h>
#include <hip/hip_bf16.h>
#include <math.h>

#define PI4F 0.78539816339744830962f

typedef __attribute__((ext_vector_type(2))) __bf16 bf16x2_t;
typedef __attribute__((ext_vector_type(8))) short s8v;      // bf16x8 MFMA operand
typedef __attribute__((ext_vector_type(4))) float f32x4;    // MFMA accumulator
typedef __attribute__((ext_vector_type(4))) unsigned int uint4v;

__device__ __forceinline__ float dot2bf(unsigned int a, unsigned int b, float c) {
#if defined(__has_builtin) && __has_builtin(__builtin_amdgcn_fdot2_f32_bf16)
    return __builtin_amdgcn_fdot2_f32_bf16(__builtin_bit_cast(bf16x2_t, a),
                                           __builtin_bit_cast(bf16x2_t, b), c, false);
#else
    float a0 = __uint_as_float(a << 16), a1 = __uint_as_float(a & 0xffff0000u);
    float b0 = __uint_as_float(b << 16), b1 = __uint_as_float(b & 0xffff0000u);
    return fmaf(a1, b1, fmaf(a0, b0, c));
#endif
}

__device__ __forceinline__ unsigned short bf16bits(float v) {
    return __builtin_bit_cast(unsigned short, __float2bfloat16(v));
}
__device__ __forceinline__ unsigned int packbf(float lo, float hi) {
    return (unsigned int)bf16bits(lo) | ((unsigned int)bf16bits(hi) << 16);
}
__device__ __forceinline__ float ubf_lo(unsigned int u) { return __uint_as_float(u << 16); }
__device__ __forceinline__ float ubf_hi(unsigned int u) { return __uint_as_float(u & 0xffff0000u); }

// ---------------- Kernel 1: global average pool (float4) ----------------
__global__ void k_pool(const float* __restrict__ x, float* __restrict__ pooled) {
    int bc = blockIdx.x;
    const float4* p4 = (const float4*)(x + (size_t)bc * 16384);
    float s = 0.f;
    for (int j = threadIdx.x; j < 4096; j += 256) {
        float4 v = p4[j];
        s += (v.x + v.y) + (v.z + v.w);
    }
    for (int off = 32; off > 0; off >>= 1) s += __shfl_xor(s, off, 64);
    __shared__ float red[4];
    int wave = threadIdx.x >> 6;
    if ((threadIdx.x & 63) == 0) red[wave] = s;
    __syncthreads();
    if (threadIdx.x == 0) {
        float t = red[0] + red[1] + red[2] + red[3];
        pooled[bc] = t * (1.0f / 16384.0f);
    }
}

// ---------------- Kernel 2: small MLPs -> angles, mod ----------------
__global__ void k_mlp(const float* __restrict__ pooled,
                      const float* __restrict__ aw1, const float* __restrict__ ab1,
                      const float* __restrict__ aw2, const float* __restrict__ ab2,
                      const float* __restrict__ mw1, const float* __restrict__ mb1,
                      const float* __restrict__ mw2, const float* __restrict__ mb2,
                      float* __restrict__ angles, float* __restrict__ mod) {
    int i = blockIdx.x >> 3, b = blockIdx.x & 7;
    int t = threadIdx.x;
    __shared__ float sp[64], sha[16], shm[16];
    sp[t] = pooled[b * 64 + t];
    __syncthreads();
    if (t < 16) {
        float sa = ab1[i * 16 + t], sm = mb1[i * 16 + t];
        const float* wa = aw1 + ((size_t)i * 16 + t) * 64;
        const float* wm = mw1 + ((size_t)i * 16 + t) * 64;
        for (int c = 0; c < 64; ++c) { sa = fmaf(wa[c], sp[c], sa); sm = fmaf(wm[c], sp[c], sm); }
        sha[t] = fmaxf(sa, 0.f);
        shm[t] = fmaxf(sm, 0.f);
    }
    __syncthreads();
    if (t < 8) {
        float s = ab2[i * 8 + t];
        const float* w = aw2 + ((size_t)i * 8 + t) * 16;
        for (int j = 0; j < 16; ++j) s = fmaf(w[j], sha[j], s);
        angles[i * 64 + b * 8 + t] = tanhf(s) * PI4F;
    }
    {
        float s = mb2[i * 64 + t];
        const float* w = mw2 + ((size_t)i * 64 + t) * 16;
        for (int j = 0; j < 16; ++j) s = fmaf(w[j], shm[j], s);
        mod[i * 512 + b * 64 + t] = 1.f / (1.f + expf(-s));
    }
}

// ---------------- Kernel 3: rotate base kernels -> MFMA-friendly bf16 pairs ----------------
__global__ void k_rot(const float* __restrict__ bk, const float* __restrict__ angles,
                      unsigned int* __restrict__ rotp) {
    int blk = blockIdx.x;
    int g = blk & 7, b = (blk >> 3) & 7, i = blk >> 6;
    float ang = angles[i * 64 + b * 8 + g];
    float st, ct;
    sincosf(ang, &st, &ct);
    int t = threadIdx.x;
    int co = t >> 3, ci = t & 7;
    const float* K = bk + ((((size_t)i * 8 + g) * 8 + co) * 8 + ci) * 9;
    __shared__ float tmp[576];
#pragma unroll
    for (int p = 0; p < 9; ++p) {
        int ky = p / 3, kx = p % 3;
        float xx = (float)kx - 1.f, yy = (float)ky - 1.f;
        float xr = xx * ct + yy * st + 1.f;
        float yr = -xx * st + yy * ct + 1.f;
        float x0 = fminf(fmaxf(floorf(xr), 0.f), 1.f);
        float y0 = fminf(fmaxf(floorf(yr), 0.f), 1.f);
        float x1 = x0 + 1.f, y1 = y0 + 1.f;
        float w00 = (x1 - xr) * (y1 - yr);
        float w01 = (x1 - xr) * (yr - y0);
        float w10 = (xr - x0) * (y1 - yr);
        float w11 = (xr - x0) * (yr - y0);
        int x0i = (int)x0, y0i = (int)y0;
        float v = w00 * K[y0i * 3 + x0i] + w01 * K[(y0i + 1) * 3 + x0i]
                + w10 * K[y0i * 3 + x0i + 1] + w11 * K[(y0i + 1) * 3 + x0i + 1];
        tmp[t * 9 + p] = v;
    }
    __syncthreads();
    unsigned int* R = rotp + (size_t)blk * 384;
    for (int ot = t; ot < 384; ot += 64) {
        int co2 = ot / 48;
        int rem = ot - co2 * 48;
        int tap = rem >> 2;
        int q = rem & 3;
        unsigned int val = 0u;
        if (tap < 9) {
            float v0 = tmp[(co2 * 8 + 2 * q) * 9 + tap];
            float v1 = tmp[(co2 * 8 + 2 * q + 1) * 9 + tap];
            val = packbf(v0, v1);
        }
        R[ot] = val;
    }
}

// ---------------- Kernel 3.5: prep (w1f, e1f, ew2p) ----------------
__global__ void k_prep(const float* __restrict__ w1,
                       const float* __restrict__ bnw, const float* __restrict__ bnb,
                       const float* __restrict__ bnm, const float* __restrict__ bnv,
                       const float* __restrict__ ew1,
                       const float* __restrict__ ebnw, const float* __restrict__ ebnb,
                       const float* __restrict__ ebnm, const float* __restrict__ ebnv,
                       const float* __restrict__ ew2,
                       unsigned int* __restrict__ w1f, float* __restrict__ dsh,
                       unsigned int* __restrict__ e1f, float* __restrict__ esh,
                       unsigned int* __restrict__ ew2p) {
    int tid = threadIdx.x;
    __shared__ float sc[64], sce[32];
    if (tid < 64) {
        float s = bnw[tid] * rsqrtf(bnv[tid] + 1e-5f);
        sc[tid] = s;
        dsh[tid] = bnb[tid] - bnm[tid] * s;
    }
    if (tid < 32) {
        float s = ebnw[tid] * rsqrtf(ebnv[tid] + 1e-5f);
        sce[tid] = s;
        esh[tid] = ebnb[tid] - ebnm[tid] * s;
    }
    __syncthreads();
    for (int q = tid; q < 8192; q += 256) {
        int jp = q & 3;
        int l  = (q >> 2) & 63;
        int ks = (q >> 8) & 7;
        int nt = q >> 11;
        int o = nt * 16 + (l & 15);
        int k = ks * 32 + (l >> 4) * 8 + jp * 2;
        w1f[q] = packbf(w1[o * 256 + k] * sc[o], w1[o * 256 + k + 1] * sc[o]);
    }
    for (int q = tid; q < 4096; q += 256) {
        int jp = q & 3;
        int l  = (q >> 2) & 63;
        int kss = (q >> 8) & 1;
        int nt8 = q >> 9;
        int o = (nt8 & 1) * 16 + (l & 15);
        int kloc = kss * 32 + (l >> 4) * 8 + jp * 2;
        e1f[q] = packbf(ew1[o * 64 + kloc] * sce[o], ew1[o * 64 + kloc + 1] * sce[o]);
    }
    for (int q = tid; q < 1024; q += 256) {
        int cc = q >> 4, c2 = q & 15;
        ew2p[q] = packbf(ew2[cc * 32 + 2 * c2], ew2[cc * 32 + 2 * c2 + 1]);
    }
}

// ---------------- Kernel 4 (unchanged): MFMA conv, pair-packed u32 out ----------------
__global__ void __launch_bounds__(256) k_conv(const float* __restrict__ x,
                       const unsigned int* __restrict__ rotp, const float* __restrict__ mod,
                       unsigned int* __restrict__ bfu) {
    __shared__ unsigned int s_in[1156 * 6];     // 27744 B
    unsigned short* s16 = (unsigned short*)s_in;

    int bg = blockIdx.y;
    int b = bg >> 3, g = bg & 7;
    int tile_h0 = (blockIdx.x >> 2) * 32;
    int tile_w0 = (blockIdx.x & 3) * 32;
    int tid = threadIdx.x;

    const float* xg = x + ((size_t)b * 64 + (size_t)g * 8) * 16384;
    for (int idx = tid; idx < 8 * 1156; idx += 256) {
        int ci = idx / 1156;
        int pix = idx - ci * 1156;
        int r = pix / 34;
        int c = pix - r * 34;
        int gh = tile_h0 + r - 1;
        int gw = tile_w0 + c - 1;
        float v = 0.f;
        if (gh >= 0 && gh < 128 && gw >= 0 && gw < 128)
            v = xg[(size_t)ci * 16384 + gh * 128 + gw];
        s16[pix * 12 + ci] = bf16bits(v);
    }
    __syncthreads();

    int l = tid & 63, wv = tid >> 6;
    int n = l & 15;
    int kg = l >> 4;

    s8v Bf[2][3];
    float mv[2];
#pragma unroll
    for (int bp = 0; bp < 2; ++bp) {
        int i = bp * 2 + (n >> 3);
        int co = n & 7;
        mv[bp] = mod[i * 512 + b * 64 + g * 8 + co];
#pragma unroll
        for (int ks = 0; ks < 3; ++ks) {
            int tap = ks * 4 + kg;
            const uint4v* src = (const uint4v*)(rotp
                + ((size_t)((i * 8 + b) * 8 + g)) * 384 + co * 48 + tap * 4);
            Bf[bp][ks] = __builtin_bit_cast(s8v, *src);
        }
    }

    int hoff6[3];
#pragma unroll
    for (int ks = 0; ks < 3; ++ks) {
        int tap = ks * 4 + kg;
        int t9 = tap > 8 ? 8 : tap;
        int ky = t9 >= 6 ? 2 : (t9 >= 3 ? 1 : 0);
        int kx = t9 - ky * 3;
        hoff6[ks] = (ky * 34 + kx) * 6;
    }

#pragma unroll 2
    for (int t = 0; t < 16; ++t) {
        int px0 = wv * 256 + t * 16;
        int trow = px0 >> 5;
        int tcolb = px0 & 31;
        int basedw = (trow * 34 + tcolb + n) * 6;

        s8v Af[3];
#pragma unroll
        for (int ks = 0; ks < 3; ++ks) {
            const uint2* pa = (const uint2*)(s_in + basedw + hoff6[ks]);
            uint2 v01 = pa[0];
            uint2 v23 = pa[1];
            uint4v au; au.x = v01.x; au.y = v01.y; au.z = v23.x; au.w = v23.y;
            Af[ks] = __builtin_bit_cast(s8v, au);
        }

#pragma unroll
        for (int bp = 0; bp < 2; ++bp) {
            f32x4 acc = (f32x4){0.f, 0.f, 0.f, 0.f};
#pragma unroll
            for (int ks = 0; ks < 3; ++ks)
                acc = __builtin_amdgcn_mfma_f32_16x16x32_bf16(Af[ks], Bf[bp][ks], acc, 0, 0, 0);

            int i = bp * 2 + (n >> 3);
            int co = n & 7;
            float a0 = acc[0] * mv[bp], a1 = acc[1] * mv[bp];
            float a2 = acc[2] * mv[bp], a3 = acc[3] * mv[bp];
            float p0 = __shfl_xor(a0, 1, 64);
            float p1 = __shfl_xor(a1, 1, 64);
            float p2 = __shfl_xor(a2, 1, 64);
            float p3 = __shfl_xor(a3, 1, 64);
            if (!(n & 1)) {
                int pxo = px0 + kg * 4;
                int orow = pxo >> 5, ocol = pxo & 31;
                uint4v st;
                st.x = packbf(a0, p0);
                st.y = packbf(a1, p1);
                st.z = packbf(a2, p2);
                st.w = packbf(a3, p3);
                unsigned int* opu = bfu
                    + (((size_t)(i * 8 + b) * 32) + g * 4 + (co >> 1)) * 16384
                    + (tile_h0 + orow) * 128 + tile_w0 + ocol;
                *(uint4v*)opu = st;
            }
        }
    }
}

// ---------------- Kernel 5 (v17): merged-pass MFMA, FULLY-unrolled ks (static acc2) ----------------
// ks fully unrolled -> nt8 = (ks>>1)*2+t2 is compile-time -> acc2 stays in registers.
// launch_bounds(256,2): 2 waves/EU -> 256-VGPR budget for acc(64)+acc2(128).
__global__ void __launch_bounds__(256, 2) k_mega(
    const float* __restrict__ x, const unsigned int* __restrict__ bfu,
    const float* __restrict__ roi,
    const unsigned int* __restrict__ w1f, const float* __restrict__ dsh,
    const float* __restrict__ w2, const float* __restrict__ b2,
    const unsigned int* __restrict__ e1f, const float* __restrict__ esh,
    const unsigned int* __restrict__ ew2p, const float* __restrict__ eb2,
    float* __restrict__ out) {

    __shared__ unsigned short y_lds[256 * 72];   // 36864 B

    int tid = threadIdx.x;
    int p = blockIdx.x * 256 + tid;
    int b = p >> 14;
    int hw = p & 16383;
    int h = hw >> 7, w = hw & 127;
    int hw_base = (blockIdx.x & 63) * 256;

    int l = tid & 63, wv = tid >> 6;
    int arow = l & 15, kg = l >> 4;

    // ---- roi bilinear (early; hides under MFMA) ----
    float ysv = (float)h * (63.f / 127.f);
    float y0f = fminf(floorf(ysv), 62.f);
    float wy = ysv - y0f;
    float xsv = (float)w * (63.f / 127.f);
    float x0f = fminf(floorf(xsv), 62.f);
    float wx = xsv - x0f;
    int y0i = (int)y0f, x0i = (int)x0f;
    const float* rb = roi + (size_t)b * 4096;
    float r00 = rb[y0i * 64 + x0i], r01 = rb[y0i * 64 + x0i + 1];
    float r10 = rb[(y0i + 1) * 64 + x0i], r11 = rb[(y0i + 1) * 64 + x0i + 1];
    float rv = r00 * (1.f - wy) * (1.f - wx) + r01 * (1.f - wy) * wx
             + r10 * wy * (1.f - wx) + r11 * wy * wx;

    // ---- merged MFMA loop (FULL unroll): y (4 nt) + m (2 static nt8) per ks ----
    f32x4 acc[4][4];
#pragma unroll
    for (int mt = 0; mt < 4; ++mt)
#pragma unroll
        for (int nt = 0; nt < 4; ++nt)
            acc[mt][nt] = (f32x4){0.f, 0.f, 0.f, 0.f};
    f32x4 acc2[8][4];   // [nt8][mt]
#pragma unroll
    for (int nt8 = 0; nt8 < 8; ++nt8)
#pragma unroll
        for (int mt = 0; mt < 4; ++mt)
            acc2[nt8][mt] = (f32x4){0.f, 0.f, 0.f, 0.f};

#pragma unroll
    for (int ks = 0; ks < 8; ++ks) {
        int k0 = ks * 32 + kg * 8;
        size_t pbase = ((size_t)((k0 >> 6) * 8 + b) * 32 + ((k0 & 63) >> 1)) * 16384;
        s8v af[4];
#pragma unroll
        for (int mt = 0; mt < 4; ++mt) {
            const unsigned int* q = bfu + pbase + hw_base + wv * 64 + mt * 16 + arow;
            uint4v au;
            au.x = q[0];
            au.y = q[16384];
            au.z = q[32768];
            au.w = q[49152];
            af[mt] = __builtin_bit_cast(s8v, au);
        }
        // y MFMAs
        s8v bfr[4];
#pragma unroll
        for (int nt = 0; nt < 4; ++nt) {
            uint4v bu = *(const uint4v*)(w1f + (((nt * 8 + ks) * 64 + l) << 2));
            bfr[nt] = __builtin_bit_cast(s8v, bu);
        }
#pragma unroll
        for (int mt = 0; mt < 4; ++mt)
#pragma unroll
            for (int nt = 0; nt < 4; ++nt)
                acc[mt][nt] = __builtin_amdgcn_mfma_f32_16x16x32_bf16(
                    af[mt], bfr[nt], acc[mt][nt], 0, 0, 0);
        // m MFMAs (block-diagonal: 2 static nt8 per ks), same af
        int kss = ks & 1;
#pragma unroll
        for (int t2 = 0; t2 < 2; ++t2) {
            int nt8 = (ks >> 1) * 2 + t2;      // compile-time (ks fully unrolled)
            uint4v bu = *(const uint4v*)(e1f + ((nt8 * 2 + kss) * 256 + l * 4));
            s8v bq = __builtin_bit_cast(s8v, bu);
#pragma unroll
            for (int mt = 0; mt < 4; ++mt)
                acc2[nt8][mt] = __builtin_amdgcn_mfma_f32_16x16x32_bf16(
                    af[mt], bq, acc2[nt8][mt], 0, 0, 0);
        }
    }

    // ---- scatter y to LDS ----
#pragma unroll
    for (int mt = 0; mt < 4; ++mt)
#pragma unroll
        for (int nt = 0; nt < 4; ++nt)
#pragma unroll
            for (int r = 0; r < 4; ++r) {
                int px = wv * 64 + mt * 16 + kg * 4 + r;
                y_lds[px * 72 + nt * 16 + arow] = bf16bits(acc[mt][nt][r]);
            }
    __syncthreads();

    // ---- gather y, bias + relu ----
    float y[64];
    {
        const uint4v* yr = (const uint4v*)(y_lds + (size_t)tid * 72);
#pragma unroll
        for (int q8 = 0; q8 < 8; ++q8) {
            uint4v v = yr[q8];
            y[q8 * 8 + 0] = ubf_lo(v.x); y[q8 * 8 + 1] = ubf_hi(v.x);
            y[q8 * 8 + 2] = ubf_lo(v.y); y[q8 * 8 + 3] = ubf_hi(v.y);
            y[q8 * 8 + 4] = ubf_lo(v.z); y[q8 * 8 + 5] = ubf_hi(v.z);
            y[q8 * 8 + 6] = ubf_lo(v.w); y[q8 * 8 + 7] = ubf_hi(v.w);
        }
    }
#pragma unroll
    for (int o = 0; o < 64; ++o) y[o] = fmaxf(y[o] + dsh[o], 0.f);

    // ---- phase 2: logits + softmax ----
    float lg[4];
#pragma unroll
    for (int k = 0; k < 4; ++k) {
        float s = b2[k];
        const float* wr = w2 + k * 64;                   // uniform
#pragma unroll
        for (int o = 0; o < 64; ++o) s = fmaf(wr[o], y[o], s);
        lg[k] = s;
    }
    float mx = fmaxf(fmaxf(lg[0], lg[1]), fmaxf(lg[2], lg[3]));
    float e0 = expf(lg[0] - mx), e1s = expf(lg[1] - mx), e2s = expf(lg[2] - mx), e3s = expf(lg[3] - mx);
    float inv = 1.f / (e0 + e1s + e2s + e3s);
    float ar = inv * rv;
    float ar0 = e0 * ar, ar1 = e1s * ar, ar2 = e2s * ar, ar3 = e3s * ar;

    float t[32];
#pragma unroll
    for (int o = 0; o < 32; ++o) t[o] = esh[o];

    // ---- round B: m0,m1 ----
    __syncthreads();
#pragma unroll
    for (int nt8 = 0; nt8 < 4; ++nt8)
#pragma unroll
        for (int mt = 0; mt < 4; ++mt)
#pragma unroll
            for (int r = 0; r < 4; ++r) {
                int px = wv * 64 + mt * 16 + kg * 4 + r;
                y_lds[px * 72 + nt8 * 16 + arow] = bf16bits(acc2[nt8][mt][r]);
            }
    __syncthreads();
    {
        const uint4v* yr = (const uint4v*)(y_lds + (size_t)tid * 72);
#pragma unroll
        for (int q8 = 0; q8 < 8; ++q8) {
            uint4v v = yr[q8];
            float arq = (q8 < 4) ? ar0 : ar1;
            int base = (q8 & 3) * 8;
            t[base + 0] = fmaf(arq, ubf_lo(v.x), t[base + 0]);
            t[base + 1] = fmaf(arq, ubf_hi(v.x), t[base + 1]);
            t[base + 2] = fmaf(arq, ubf_lo(v.y), t[base + 2]);
            t[base + 3] = fmaf(arq, ubf_hi(v.y), t[base + 3]);
            t[base + 4] = fmaf(arq, ubf_lo(v.z), t[base + 4]);
            t[base + 5] = fmaf(arq, ubf_hi(v.z), t[base + 5]);
            t[base + 6] = fmaf(arq, ubf_lo(v.w), t[base + 6]);
            t[base + 7] = fmaf(arq, ubf_hi(v.w), t[base + 7]);
        }
    }

    // ---- round C: m2,m3 ----
    __syncthreads();
#pragma unroll
    for (int nt8 = 4; nt8 < 8; ++nt8)
#pragma unroll
        for (int mt = 0; mt < 4; ++mt)
#pragma unroll
            for (int r = 0; r < 4; ++r) {
                int px = wv * 64 + mt * 16 + kg * 4 + r;
                y_lds[px * 72 + (nt8 - 4) * 16 + arow] = bf16bits(acc2[nt8][mt][r]);
            }
    __syncthreads();
    {
        const uint4v* yr = (const uint4v*)(y_lds + (size_t)tid * 72);
#pragma unroll
        for (int q8 = 0; q8 < 8; ++q8) {
            uint4v v = yr[q8];
            float arq = (q8 < 4) ? ar2 : ar3;
            int base = (q8 & 3) * 8;
            t[base + 0] = fmaf(arq, ubf_lo(v.x), t[base + 0]);
            t[base + 1] = fmaf(arq, ubf_hi(v.x), t[base + 1]);
            t[base + 2] = fmaf(arq, ubf_lo(v.y), t[base + 2]);
            t[base + 3] = fmaf(arq, ubf_hi(v.y), t[base + 3]);
            t[base + 4] = fmaf(arq, ubf_lo(v.z), t[base + 4]);
            t[base + 5] = fmaf(arq, ubf_hi(v.z), t[base + 5]);
            t[base + 6] = fmaf(arq, ubf_lo(v.w), t[base + 6]);
            t[base + 7] = fmaf(arq, ubf_hi(v.w), t[base + 7]);
        }
    }

    // ---- eh = relu(t), pack ----
    unsigned int ehp[16];
#pragma unroll
    for (int q = 0; q < 16; ++q)
        ehp[q] = packbf(fmaxf(t[2 * q], 0.f), fmaxf(t[2 * q + 1], 0.f));

    // ---- phase 6: e2 = sigmoid(ew2 @ eh + b), out = x*(1+e2) ----
    const float* xp = x + ((size_t)b * 64) * 16384 + hw;
    float* op = out + ((size_t)b * 64) * 16384 + hw;
#pragma unroll 8
    for (int cc = 0; cc < 64; ++cc) {
        float s = eb2[cc];
        const unsigned int* wr = ew2p + cc * 16;         // uniform -> SGPR
#pragma unroll
        for (int q = 0; q < 16; ++q) s = dot2bf(ehp[q], wr[q], s);
        float sg = 1.f / (1.f + expf(-s));
        float xv = xp[(size_t)cc * 16384];
        op[(size_t)cc * 16384] = xv + xv * sg;
    }
}

extern "C" void kernel_launch(void* const* d_in, const int* in_sizes, int n_in,
                              void* d_out, int out_size, void* d_ws, size_t ws_size,
                              hipStream_t stream) {
    const float* x    = (const float*)d_in[0];
    const float* roi  = (const float*)d_in[1];
    const float* bk   = (const float*)d_in[2];
    const float* aw1  = (const float*)d_in[3];
    const float* ab1  = (const float*)d_in[4];
    const float* aw2  = (const float*)d_in[5];
    const float* ab2  = (const float*)d_in[6];
    const float* mw1  = (const float*)d_in[7];
    const float* mb1  = (const float*)d_in[8];
    const float* mw2  = (const float*)d_in[9];
    const float* mb2  = (const float*)d_in[10];
    const float* w1   = (const float*)d_in[11];
    const float* bnw  = (const float*)d_in[12];
    const float* bnb  = (const float*)d_in[13];
    const float* bnm  = (const float*)d_in[14];
    const float* bnv  = (const float*)d_in[15];
    const float* w2   = (const float*)d_in[16];
    const float* b2   = (const float*)d_in[17];
    const float* ew1  = (const float*)d_in[18];
    const float* ebnw = (const float*)d_in[19];
    const float* ebnb = (const float*)d_in[20];
    const float* ebnm = (const float*)d_in[21];
    const float* ebnv = (const float*)d_in[22];
    const float* ew2  = (const float*)d_in[23];
    const float* eb2  = (const float*)d_in[24];

    float* ws     = (float*)d_ws;
    float* pooled = ws;                    // 512
    float* angles = ws + 512;              // 256
    float* mod    = ws + 768;              // 2048
    unsigned int* rotp = (unsigned int*)(ws + 2816);   // 98304 u32
    unsigned int* w1f  = (unsigned int*)(ws + 150272); // 8192 u32
    float* dsh    = ws + 158464;           // 64
    float* esh    = ws + 158528;           // 32
    unsigned int* ew2p = (unsigned int*)(ws + 158560); // 1024
    unsigned int* e1f  = (unsigned int*)(ws + 159584); // 4096
    unsigned int* bfu  = (unsigned int*)(ws + 166720); // 16M u32 = 64 MB

    k_prep<<<1, 256, 0, stream>>>(w1, bnw, bnb, bnm, bnv,
                                  ew1, ebnw, ebnb, ebnm, ebnv, ew2,
                                  w1f, dsh, e1f, esh, ew2p);
    k_pool<<<512, 256, 0, stream>>>(x, pooled);
    k_mlp<<<32, 64, 0, stream>>>(pooled, aw1, ab1, aw2, ab2, mw1, mb1, mw2, mb2, angles, mod);
    k_rot<<<256, 64, 0, stream>>>(bk, angles, rotp);
    k_conv<<<dim3(16, 64), 256, 0, stream>>>(x, rotp, mod, bfu);
    k_mega<<<512, 256, 0, stream>>>(x, bfu, roi, w1f, dsh, w2, b2,
                                    e1f, esh, ew2p, eb2,
                                    (float*)d_out);
}